// Round 12
// baseline (360.071 us; speedup 1.0000x reference)
//
#include <hip/hip_runtime.h>
#include <stdint.h>

#define NR 8192
#define DD 128

typedef __attribute__((ext_vector_type(4))) int int32x4;
typedef __attribute__((ext_vector_type(8))) int int32x8;
typedef __attribute__((ext_vector_type(4))) float f32x4;

#ifdef __has_builtin
#if __has_builtin(__builtin_amdgcn_exp2f)
#define EXP2F __builtin_amdgcn_exp2f
#endif
#endif
#ifndef EXP2F
#define EXP2F exp2f
#endif

// exp(10*x) == exp2(x * 10/ln2).  10/ln2 folded into the stored values:
// q = e4m3( sqrt(10/ln2) * normalized ), so every pairwise product (MFMA
// dot, p0 elementwise, diag) is already the exp2 argument.
#define SQK 3.79828255f     // sqrt(10/ln2)
#define SCALE1 0x7F7F7F7F   // e8m0 127 = 2^0 in every byte

// ---- OCP e4m3fn software encode (RNE) / decode (exact) --------------------
__device__ __forceinline__ uint32_t enc_e4m3(float x) {
  uint32_t u = __float_as_uint(x);
  uint32_t s = (u >> 31) << 7;
  float ax = fabsf(x);
  if (ax < 0.015625f) {                 // subnormal target: m * 2^-9
    int m = (int)rintf(ax * 512.0f);    // RNE; 0..8
    return (m >= 8) ? (s | (1u << 3)) : (s | (uint32_t)m);
  }
  uint32_t v = u & 0x7FFFFFFFu;
  v += 0x7FFFFu + ((v >> 20) & 1u);     // RNE to 3 mantissa bits
  int e = (int)((v >> 23) & 255u) - 127;
  uint32_t m3 = (v >> 20) & 7u;
  return s | ((uint32_t)(e + 7) << 3) | m3;   // |x| <= ~2 -> no overflow
}
__device__ __forceinline__ float dec_e4m3(uint32_t b) {
  uint32_t s = b >> 7, e = (b >> 3) & 15u, m = b & 7u;
  float v = e ? __uint_as_float(((e + 120u) << 23) | (m << 20))
              : (float)m * 0.001953125f;      // m * 2^-9
  return s ? -v : v;
}

// ---------------------------------------------------------------------------
// K1: row L2-normalize (fp32), emit e4m3 copies scaled by SQK, diag =
// sum(dequant^2) (== the MFMA Gram diagonal).  Zeroes sums and d_out.
// ---------------------------------------------------------------------------
__global__ __launch_bounds__(256) void k_normalize(
    const float* __restrict__ u1, const float* __restrict__ u2,
    const float* __restrict__ i1, const float* __restrict__ i2,
    uint8_t* __restrict__ nb, float* __restrict__ diag,
    float* __restrict__ sums, float* __restrict__ out)
{
  int tid = threadIdx.x;
  int gid = blockIdx.x * 256 + tid;
  if (gid < 6 * NR) sums[gid] = 0.0f;
  if (gid == 0) out[0] = 0.0f;

  int w = tid >> 6, lane = tid & 63;
  int rowId = blockIdx.x * 4 + w;            // 0..32767
  int mi = rowId >> 13, r = rowId & (NR - 1);
  const float* src = (mi == 0) ? u1 : (mi == 1) ? u2 : (mi == 2) ? i1 : i2;
  const float2 v = *(const float2*)(src + (size_t)r * DD + lane * 2);
  float ss = v.x * v.x + v.y * v.y;
#pragma unroll
  for (int off = 32; off >= 1; off >>= 1) ss += __shfl_xor(ss, off, 64);
  float sc = SQK / fmaxf(sqrtf(ss), 1e-12f);
  uint32_t c0 = enc_e4m3(v.x * sc);
  uint32_t c1 = enc_e4m3(v.y * sc);
  uint8_t* dst = nb + (size_t)mi * NR * DD + (size_t)r * DD + lane * 2;
  *(uint16_t*)dst = (uint16_t)(c0 | (c1 << 8));
  float d0 = dec_e4m3(c0), d1 = dec_e4m3(c1);
  float dd = d0 * d0 + d1 * d1;
#pragma unroll
  for (int off = 32; off >= 1; off >>= 1) dd += __shfl_xor(dd, off, 64);
  if (lane == 0) diag[rowId] = dd;
}

// ---------------------------------------------------------------------------
// K2: Gram row-sums, MX-fp8.  r10 structure verbatim (6 full Grams,
// triple-buffered 8KB LDS tiles, counted-vmcnt + raw barrier per tile,
// one mfma_scale_f32_16x16x128 per (m,c)) with ONE change: occupancy.
//   grid 768 -> 1536 (8 col-chunks x 16 tiles instead of 4 x 32) and
//   __launch_bounds__(256, 6): 6 blocks/CU (VGPR cap 85 >= 64 used;
//   LDS 6 x 24KB = 144 <= 160KB).  25% -> ~56% occupancy gives the
//   m114 MFMA-wave || VALU-wave co-issue the wave diversity it needs
//   (r10 overlap factor was only ~1.17 at 3 waves/SIMD).
// ---------------------------------------------------------------------------
__global__ __launch_bounds__(256, 6) void k_gram(
    const uint8_t* __restrict__ nb, float* __restrict__ sums)
{
  __shared__ alignas(16) uint8_t ldsB[3][64 * DD];   // 3 x 8 KB

  // bijective XCD-chunk swizzle: 1536 = 8 * 192
  int bid = (blockIdx.x & 7) * 192 + (blockIdx.x >> 3);
  int job = bid >> 8;          // 256 blocks per job
  int rem = bid & 255;
  int rb = rem >> 3;           // row-block 0..31 (256 rows each)
  int cs = rem & 7;            // col-chunk 0..7  (1024 cols each)
  const int ja[6] = {0, 0, 1, 2, 2, 3};
  const int jb[6] = {1, 0, 1, 3, 2, 3};
  const uint8_t* A = nb + (size_t)ja[job] * NR * DD;
  const uint8_t* B = nb + (size_t)jb[job] * NR * DD;
  float* out = sums + job * NR;

  int tid = threadIdx.x, w = tid >> 6, lane = tid & 63;
  int l15 = lane & 15, lg = lane >> 4;
  int rowBase = rb * 256 + w * 64;

  const char* Bb = (const char*)B;
  char* ldsbase = (char*)&ldsB[0][0];
  int jstart = cs * 1024;

  // stage one 64-col tile (8KB): linear LDS dest, inverse-swizzled source
  // (rule #21).  2 x global_load_lds_dwordx4 per wave.
#define STAGE(dst, jt)                                                        \
  {                                                                           \
    const char* tbase = Bb + (size_t)(jstart + (jt) * 64) * 128;              \
    _Pragma("unroll")                                                         \
    for (int it = 0; it < 2; ++it) {                                          \
      int dbase = it * 4096 + w * 1024;                                       \
      int doff = dbase + lane * 16;                                           \
      int soff = doff ^ (((doff >> 7) & 7) << 4);                             \
      __builtin_amdgcn_global_load_lds(                                       \
          (const __attribute__((address_space(1))) void*)(tbase + soff),      \
          (__attribute__((address_space(3))) void*)((dst) + dbase),           \
          16, 0, 0);                                                          \
    }                                                                         \
  }

#define COMPUTE(bufc)                                                         \
  {                                                                           \
    _Pragma("unroll")                                                         \
    for (int c = 0; c < 4; ++c) {                                             \
      int r = c * 16 + l15;                                                   \
      int base = r * 128 + lg * 32;                                           \
      int swz = (r & 7) << 4;                                                 \
      int32x4 blo = *(const int32x4*)((bufc) + (base ^ swz));                 \
      int32x4 bhi = *(const int32x4*)((bufc) + ((base + 16) ^ swz));          \
      int32x8 b8 = __builtin_shufflevector(blo, bhi, 0, 1, 2, 3, 4, 5, 6, 7); \
      _Pragma("unroll")                                                       \
      for (int m = 0; m < 4; ++m) {                                           \
        f32x4 acc = {0.0f, 0.0f, 0.0f, 0.0f};                                 \
        acc = __builtin_amdgcn_mfma_scale_f32_16x16x128_f8f6f4(               \
            af[m], b8, acc, 0, 0, 0, SCALE1, 0, SCALE1);                      \
        _Pragma("unroll")                                                     \
        for (int j = 0; j < 4; ++j)                                           \
          racc[m][j] += EXP2F(acc[j]);                                        \
      }                                                                       \
    }                                                                         \
  }

  // prologue: stage tile 0; A-frag loads fly under it; one full drain.
  STAGE(ldsbase, 0);

  // A fragments: row rowBase+m*16+l15, k-bytes [lg*32, lg*32+32)
  int32x8 af[4];
#pragma unroll
  for (int m = 0; m < 4; ++m)
    af[m] = *(const int32x8*)(A + (size_t)(rowBase + m * 16 + l15) * DD + lg * 32);

  float racc[4][4];
#pragma unroll
  for (int m = 0; m < 4; ++m)
#pragma unroll
    for (int j = 0; j < 4; ++j) racc[m][j] = 0.0f;

  asm volatile("s_waitcnt vmcnt(0)" ::: "memory");
  __builtin_amdgcn_s_barrier();
  __builtin_amdgcn_sched_barrier(0);

  // main loop: counted-vmcnt pipeline, ONE raw barrier per tile
  int cur = 0;
  for (int jt = 0; jt < 15; ++jt) {
    int nxt = cur + 1; if (nxt == 3) nxt = 0;
    STAGE(ldsbase + nxt * 8192, jt + 1);   // 2 loads issued, stay in flight
    __builtin_amdgcn_sched_barrier(0);
    asm volatile("s_waitcnt vmcnt(2)" ::: "memory");  // stage(jt) retired
    __builtin_amdgcn_s_barrier();                     // ...in ALL waves
    __builtin_amdgcn_sched_barrier(0);
    COMPUTE(ldsbase + cur * 8192);
    cur = nxt;
  }
  // epilogue: tile 15
  __builtin_amdgcn_sched_barrier(0);
  asm volatile("s_waitcnt vmcnt(0)" ::: "memory");
  __builtin_amdgcn_s_barrier();
  __builtin_amdgcn_sched_barrier(0);
  COMPUTE(ldsbase + cur * 8192);

  // row-sums: reduce over the 16 lanes (cols) in each lg group
#pragma unroll
  for (int off = 1; off < 16; off <<= 1)
#pragma unroll
    for (int m = 0; m < 4; ++m)
#pragma unroll
      for (int j = 0; j < 4; ++j)
        racc[m][j] += __shfl_xor(racc[m][j], off, 64);

  if (l15 == 0) {
#pragma unroll
    for (int m = 0; m < 4; ++m)
#pragma unroll
      for (int j = 0; j < 4; ++j)
        atomicAdd(&out[rowBase + m * 16 + lg * 4 + j], racc[m][j]);
  }
#undef STAGE
#undef COMPUTE
}

// ---------------------------------------------------------------------------
// K3: finalize.  16 rows per wave, one atomic per BLOCK (256 total).
// loss += log(s12+s11+p0) + log(s12+s22+p0) - 2*log(p0);  out = loss/4.
// ---------------------------------------------------------------------------
__global__ __launch_bounds__(256) void k_finalize(
    const uint8_t* __restrict__ nb, const float* __restrict__ diag,
    const float* __restrict__ sums, float* __restrict__ out)
{
  __shared__ float part[4];
  int tid = threadIdx.x, w = tid >> 6, lane = tid & 63;
  int waveId = blockIdx.x * 4 + w;        // 0..1023
  float local = 0.0f;

  for (int i = 0; i < 16; ++i) {
    int rowId = waveId * 16 + i;          // 0..16383
    int p = rowId >> 13, r = rowId & (NR - 1);
    const uint8_t* n1 = nb + (size_t)(2 * p) * NR * DD + (size_t)r * DD;
    const uint8_t* n2 = n1 + (size_t)NR * DD;
    uint32_t a = *(const uint16_t*)(n1 + lane * 2);
    uint32_t b = *(const uint16_t*)(n2 + lane * 2);
    float a0 = dec_e4m3(a & 0xFFu), a1 = dec_e4m3(a >> 8);
    float b0 = dec_e4m3(b & 0xFFu), b1 = dec_e4m3(b >> 8);
    // values pre-scaled by SQK: product is already the exp2 argument
    float p0 = EXP2F(a0 * b0) + EXP2F(a1 * b1);
#pragma unroll
    for (int off = 32; off >= 1; off >>= 1) p0 += __shfl_xor(p0, off, 64);

    if (lane == 0) {
      const float* s12v = sums + (3 * p) * NR;
      const float* s11v = sums + (3 * p + 1) * NR;
      const float* s22v = sums + (3 * p + 2) * NR;
      float e1 = EXP2F(diag[(2 * p) * NR + r]);
      float e2 = EXP2F(diag[(2 * p + 1) * NR + r]);
      float s12 = s12v[r];
      float S1 = s12 + (s11v[r] - e1) + p0;
      float S2 = s12 + (s22v[r] - e2) + p0;
      local += logf(S1) + logf(S2) - 2.0f * logf(p0);
    }
  }
  if (lane == 0) part[w] = local;
  __syncthreads();
  if (tid == 0) {
    float t = part[0] + part[1] + part[2] + part[3];
    atomicAdd(out, 0.25f * t);
  }
}

// ---------------------------------------------------------------------------
extern "C" void kernel_launch(void* const* d_in, const int* in_sizes, int n_in,
                              void* d_out, int out_size, void* d_ws, size_t ws_size,
                              hipStream_t stream) {
  const float* u1 = (const float*)d_in[0];
  const float* u2 = (const float*)d_in[1];
  const float* i1 = (const float*)d_in[2];
  const float* i2 = (const float*)d_in[3];

  // ws layout: 4 e4m3 matrices (4 MB) | diag[4][NR] f32 | sums[6][NR] f32
  uint8_t* nb = (uint8_t*)d_ws;
  float* diag = (float*)((char*)d_ws + (size_t)4 * NR * DD);
  float* sums = diag + 4 * NR;
  float* out = (float*)d_out;

  k_normalize<<<NR * 4 / 4, 256, 0, stream>>>(u1, u2, i1, i2, nb, diag, sums, out);
  k_gram<<<1536, 256, 0, stream>>>(nb, sums);
  k_finalize<<<256, 256, 0, stream>>>(nb, diag, sums, out);
}

// Round 13
// 94.619 us; speedup vs baseline: 3.8055x; 3.8055x over previous
//
#include <hip/hip_runtime.h>
#include <stdint.h>

#define NR 8192
#define DD 128

typedef __attribute__((ext_vector_type(4))) int int32x4;
typedef __attribute__((ext_vector_type(8))) int int32x8;
typedef __attribute__((ext_vector_type(4))) float f32x4;

#ifdef __has_builtin
#if __has_builtin(__builtin_amdgcn_exp2f)
#define EXP2F __builtin_amdgcn_exp2f
#endif
#endif
#ifndef EXP2F
#define EXP2F exp2f
#endif

// exp(10*x) == exp2(x * 10/ln2).  10/ln2 folded into the stored values:
// q = e4m3( sqrt(10/ln2) * normalized ), so every pairwise product (MFMA
// dot, p0 elementwise, diag) is already the exp2 argument.
#define SQK 3.79828255f     // sqrt(10/ln2)
#define SCALE1 0x7F7F7F7F   // e8m0 127 = 2^0 in every byte

// ---- OCP e4m3fn software encode (RNE) / decode (exact) --------------------
__device__ __forceinline__ uint32_t enc_e4m3(float x) {
  uint32_t u = __float_as_uint(x);
  uint32_t s = (u >> 31) << 7;
  float ax = fabsf(x);
  if (ax < 0.015625f) {                 // subnormal target: m * 2^-9
    int m = (int)rintf(ax * 512.0f);    // RNE; 0..8
    return (m >= 8) ? (s | (1u << 3)) : (s | (uint32_t)m);
  }
  uint32_t v = u & 0x7FFFFFFFu;
  v += 0x7FFFFu + ((v >> 20) & 1u);     // RNE to 3 mantissa bits
  int e = (int)((v >> 23) & 255u) - 127;
  uint32_t m3 = (v >> 20) & 7u;
  return s | ((uint32_t)(e + 7) << 3) | m3;   // |x| <= ~2 -> no overflow
}
__device__ __forceinline__ float dec_e4m3(uint32_t b) {
  uint32_t s = b >> 7, e = (b >> 3) & 15u, m = b & 7u;
  float v = e ? __uint_as_float(((e + 120u) << 23) | (m << 20))
              : (float)m * 0.001953125f;      // m * 2^-9
  return s ? -v : v;
}

// ---------------------------------------------------------------------------
// K1: row L2-normalize (fp32), emit e4m3 copies scaled by SQK, diag =
// sum(dequant^2) (== the MFMA Gram diagonal).  Zeroes sums and d_out.
// ---------------------------------------------------------------------------
__global__ __launch_bounds__(256) void k_normalize(
    const float* __restrict__ u1, const float* __restrict__ u2,
    const float* __restrict__ i1, const float* __restrict__ i2,
    uint8_t* __restrict__ nb, float* __restrict__ diag,
    float* __restrict__ sums, float* __restrict__ out)
{
  int tid = threadIdx.x;
  int gid = blockIdx.x * 256 + tid;
  if (gid < 6 * NR) sums[gid] = 0.0f;
  if (gid == 0) out[0] = 0.0f;

  int w = tid >> 6, lane = tid & 63;
  int rowId = blockIdx.x * 4 + w;            // 0..32767
  int mi = rowId >> 13, r = rowId & (NR - 1);
  const float* src = (mi == 0) ? u1 : (mi == 1) ? u2 : (mi == 2) ? i1 : i2;
  const float2 v = *(const float2*)(src + (size_t)r * DD + lane * 2);
  float ss = v.x * v.x + v.y * v.y;
#pragma unroll
  for (int off = 32; off >= 1; off >>= 1) ss += __shfl_xor(ss, off, 64);
  float sc = SQK / fmaxf(sqrtf(ss), 1e-12f);
  uint32_t c0 = enc_e4m3(v.x * sc);
  uint32_t c1 = enc_e4m3(v.y * sc);
  uint8_t* dst = nb + (size_t)mi * NR * DD + (size_t)r * DD + lane * 2;
  *(uint16_t*)dst = (uint16_t)(c0 | (c1 << 8));
  float d0 = dec_e4m3(c0), d1 = dec_e4m3(c1);
  float dd = d0 * d0 + d1 * d1;
#pragma unroll
  for (int off = 32; off >= 1; off >>= 1) dd += __shfl_xor(dd, off, 64);
  if (lane == 0) diag[rowId] = dd;
}

// ---------------------------------------------------------------------------
// K2: Gram row-sums, MX-fp8, FLATTENED-UNIFORM grid for 4 blocks/CU.
// Global tile index t in [0, 24576): job = t>>12, rb = (t>>7)&31, ct = t&127.
// 1024 blocks x 24 tiles each (exact).  A block's run crosses a row-panel
// boundary at most once (block-uniform branch): flush racc -> atomics,
// reload A-frags, continue.  Inner loop is the r10-verified pipeline:
// triple-buffered 8KB tiles, counted vmcnt(2), one raw barrier per tile,
// one mfma_scale_f32_16x16x128 per (m,c).
// __launch_bounds__(256,4): VGPR cap 128 >> 64 used (r4/r12 spill cliffs
// were caps of 64/85 vs need; 128 cannot squeeze).  LDS 4x24KB=96<=160KB.
// ---------------------------------------------------------------------------
__global__ __launch_bounds__(256, 4) void k_gram(
    const uint8_t* __restrict__ nb, float* __restrict__ sums)
{
  __shared__ alignas(16) uint8_t ldsB[3][64 * DD];   // 3 x 8 KB

  // bijective XCD-chunk swizzle: 1024 = 8 * 128
  int bid = (blockIdx.x & 7) * 128 + (blockIdx.x >> 3);
  int t0 = bid * 24;

  const int ja[6] = {0, 0, 1, 2, 2, 3};
  const int jb[6] = {1, 0, 1, 3, 2, 3};

  int tid = threadIdx.x, w = tid >> 6, lane = tid & 63;
  int l15 = lane & 15, lg = lane >> 4;

  char* ldsbase = (char*)&ldsB[0][0];

  // B byte base of tile t (job's B matrix, col-tile ct)
#define BPTR(t) ((const char*)nb + (size_t)jb[(t) >> 12] * (NR * DD) +        \
                 (size_t)((t) & 127) * 8192)

  // stage one 64-col tile (8KB): linear LDS dest, inverse-swizzled source
#define STAGE(dst, t)                                                         \
  {                                                                           \
    const char* tbase = BPTR(t);                                              \
    _Pragma("unroll")                                                         \
    for (int it = 0; it < 2; ++it) {                                          \
      int dbase = it * 4096 + w * 1024;                                       \
      int doff = dbase + lane * 16;                                           \
      int soff = doff ^ (((doff >> 7) & 7) << 4);                             \
      __builtin_amdgcn_global_load_lds(                                       \
          (const __attribute__((address_space(1))) void*)(tbase + soff),      \
          (__attribute__((address_space(3))) void*)((dst) + dbase),           \
          16, 0, 0);                                                          \
    }                                                                         \
  }

  // A fragments for panel p: row (p&31)*256 + w*64 + m*16 + l15, k = lg*32..
#define LOAD_AF(p)                                                            \
  {                                                                           \
    const uint8_t* Ap = nb + (size_t)ja[(p) >> 5] * (NR * DD);                \
    int rowB = ((p) & 31) * 256 + w * 64;                                     \
    _Pragma("unroll")                                                         \
    for (int m = 0; m < 4; ++m)                                               \
      af[m] = *(const int32x8*)(Ap + (size_t)(rowB + m * 16 + l15) * DD +     \
                                lg * 32);                                     \
  }

#define COMPUTE(bufc)                                                         \
  {                                                                           \
    _Pragma("unroll")                                                         \
    for (int c = 0; c < 4; ++c) {                                             \
      int r = c * 16 + l15;                                                   \
      int base = r * 128 + lg * 32;                                           \
      int swz = (r & 7) << 4;                                                 \
      int32x4 blo = *(const int32x4*)((bufc) + (base ^ swz));                 \
      int32x4 bhi = *(const int32x4*)((bufc) + ((base + 16) ^ swz));          \
      int32x8 b8 = __builtin_shufflevector(blo, bhi, 0, 1, 2, 3, 4, 5, 6, 7); \
      _Pragma("unroll")                                                       \
      for (int m = 0; m < 4; ++m) {                                           \
        f32x4 acc = {0.0f, 0.0f, 0.0f, 0.0f};                                 \
        acc = __builtin_amdgcn_mfma_scale_f32_16x16x128_f8f6f4(               \
            af[m], b8, acc, 0, 0, 0, SCALE1, 0, SCALE1);                      \
        _Pragma("unroll")                                                     \
        for (int j = 0; j < 4; ++j)                                           \
          racc[m][j] += EXP2F(acc[j]);                                        \
      }                                                                       \
    }                                                                         \
  }

  // flush row-sums of panel p (shuffle-reduce over 16 col-lanes + atomics),
  // then zero racc.
#define FLUSHR(p)                                                             \
  {                                                                           \
    _Pragma("unroll")                                                         \
    for (int off = 1; off < 16; off <<= 1)                                    \
      _Pragma("unroll")                                                       \
      for (int m = 0; m < 4; ++m)                                             \
        _Pragma("unroll")                                                     \
        for (int j = 0; j < 4; ++j)                                           \
          racc[m][j] += __shfl_xor(racc[m][j], off, 64);                      \
    if (l15 == 0) {                                                           \
      float* outp = sums + ((p) >> 5) * NR + ((p) & 31) * 256 + w * 64;       \
      _Pragma("unroll")                                                       \
      for (int m = 0; m < 4; ++m)                                             \
        _Pragma("unroll")                                                     \
        for (int j = 0; j < 4; ++j)                                           \
          atomicAdd(&outp[m * 16 + lg * 4 + j], racc[m][j]);                  \
    }                                                                         \
    _Pragma("unroll")                                                         \
    for (int m = 0; m < 4; ++m)                                               \
      _Pragma("unroll")                                                       \
      for (int j = 0; j < 4; ++j) racc[m][j] = 0.0f;                          \
  }

  // prologue: stage tile t0; A-frag loads fly under it; one full drain.
  STAGE(ldsbase, t0);

  int32x8 af[4];
  int curPanel = t0 >> 7;
  LOAD_AF(curPanel);

  float racc[4][4];
#pragma unroll
  for (int m = 0; m < 4; ++m)
#pragma unroll
    for (int j = 0; j < 4; ++j) racc[m][j] = 0.0f;

  asm volatile("s_waitcnt vmcnt(0)" ::: "memory");
  __builtin_amdgcn_s_barrier();
  __builtin_amdgcn_sched_barrier(0);

  // main loop: counted-vmcnt pipeline, ONE raw barrier per tile
  int cur = 0;
  for (int jt = 0; jt < 23; ++jt) {
    int t = t0 + jt;
    int nxt = cur + 1; if (nxt == 3) nxt = 0;
    STAGE(ldsbase + nxt * 8192, t + 1);    // 2 loads issued, stay in flight
    __builtin_amdgcn_sched_barrier(0);
    asm volatile("s_waitcnt vmcnt(2)" ::: "memory");  // stage(t) retired
    __builtin_amdgcn_s_barrier();                     // ...in ALL waves
    __builtin_amdgcn_sched_barrier(0);
    COMPUTE(ldsbase + cur * 8192);
    int npanel = (t + 1) >> 7;
    if (npanel != curPanel) {              // block-uniform; <=1 per block
      FLUSHR(curPanel);
      LOAD_AF(npanel);
      curPanel = npanel;
    }
    cur = nxt;
  }
  // epilogue: last tile
  __builtin_amdgcn_sched_barrier(0);
  asm volatile("s_waitcnt vmcnt(0)" ::: "memory");
  __builtin_amdgcn_s_barrier();
  __builtin_amdgcn_sched_barrier(0);
  COMPUTE(ldsbase + cur * 8192);
  FLUSHR(curPanel);

#undef BPTR
#undef STAGE
#undef LOAD_AF
#undef COMPUTE
#undef FLUSHR
}

// ---------------------------------------------------------------------------
// K3: finalize.  16 rows per wave, one atomic per BLOCK (256 total).
// loss += log(s12+s11+p0) + log(s12+s22+p0) - 2*log(p0);  out = loss/4.
// ---------------------------------------------------------------------------
__global__ __launch_bounds__(256) void k_finalize(
    const uint8_t* __restrict__ nb, const float* __restrict__ diag,
    const float* __restrict__ sums, float* __restrict__ out)
{
  __shared__ float part[4];
  int tid = threadIdx.x, w = tid >> 6, lane = tid & 63;
  int waveId = blockIdx.x * 4 + w;        // 0..1023
  float local = 0.0f;

  for (int i = 0; i < 16; ++i) {
    int rowId = waveId * 16 + i;          // 0..16383
    int p = rowId >> 13, r = rowId & (NR - 1);
    const uint8_t* n1 = nb + (size_t)(2 * p) * NR * DD + (size_t)r * DD;
    const uint8_t* n2 = n1 + (size_t)NR * DD;
    uint32_t a = *(const uint16_t*)(n1 + lane * 2);
    uint32_t b = *(const uint16_t*)(n2 + lane * 2);
    float a0 = dec_e4m3(a & 0xFFu), a1 = dec_e4m3(a >> 8);
    float b0 = dec_e4m3(b & 0xFFu), b1 = dec_e4m3(b >> 8);
    // values pre-scaled by SQK: product is already the exp2 argument
    float p0 = EXP2F(a0 * b0) + EXP2F(a1 * b1);
#pragma unroll
    for (int off = 32; off >= 1; off >>= 1) p0 += __shfl_xor(p0, off, 64);

    if (lane == 0) {
      const float* s12v = sums + (3 * p) * NR;
      const float* s11v = sums + (3 * p + 1) * NR;
      const float* s22v = sums + (3 * p + 2) * NR;
      float e1 = EXP2F(diag[(2 * p) * NR + r]);
      float e2 = EXP2F(diag[(2 * p + 1) * NR + r]);
      float s12 = s12v[r];
      float S1 = s12 + (s11v[r] - e1) + p0;
      float S2 = s12 + (s22v[r] - e2) + p0;
      local += logf(S1) + logf(S2) - 2.0f * logf(p0);
    }
  }
  if (lane == 0) part[w] = local;
  __syncthreads();
  if (tid == 0) {
    float t = part[0] + part[1] + part[2] + part[3];
    atomicAdd(out, 0.25f * t);
  }
}

// ---------------------------------------------------------------------------
extern "C" void kernel_launch(void* const* d_in, const int* in_sizes, int n_in,
                              void* d_out, int out_size, void* d_ws, size_t ws_size,
                              hipStream_t stream) {
  const float* u1 = (const float*)d_in[0];
  const float* u2 = (const float*)d_in[1];
  const float* i1 = (const float*)d_in[2];
  const float* i2 = (const float*)d_in[3];

  // ws layout: 4 e4m3 matrices (4 MB) | diag[4][NR] f32 | sums[6][NR] f32
  uint8_t* nb = (uint8_t*)d_ws;
  float* diag = (float*)((char*)d_ws + (size_t)4 * NR * DD);
  float* sums = diag + 4 * NR;
  float* out = (float*)d_out;

  k_normalize<<<NR * 4 / 4, 256, 0, stream>>>(u1, u2, i1, i2, nb, diag, sums, out);
  k_gram<<<1024, 256, 0, stream>>>(nb, sums);
  k_finalize<<<256, 256, 0, stream>>>(nb, diag, sums, out);
}

// Round 14
// 78.091 us; speedup vs baseline: 4.6109x; 1.2116x over previous
//
#include <hip/hip_runtime.h>
#include <stdint.h>

#define NR 8192
#define DD 128

typedef __attribute__((ext_vector_type(4))) int int32x4;
typedef __attribute__((ext_vector_type(8))) int int32x8;
typedef __attribute__((ext_vector_type(4))) float f32x4;

#ifdef __has_builtin
#if __has_builtin(__builtin_amdgcn_exp2f)
#define EXP2F __builtin_amdgcn_exp2f
#endif
#endif
#ifndef EXP2F
#define EXP2F exp2f
#endif

// exp(10*x) == exp2(x * 10/ln2).  10/ln2 folded into the stored values:
// q = e4m3( sqrt(10/ln2) * normalized ), so every pairwise product (MFMA
// dot, p0 elementwise, diag) is already the exp2 argument.
#define SQK 3.79828255f     // sqrt(10/ln2)
#define SCALE1 0x7F7F7F7F   // e8m0 127 = 2^0 in every byte

// ---- OCP e4m3fn software encode (RNE) / decode (exact) --------------------
__device__ __forceinline__ uint32_t enc_e4m3(float x) {
  uint32_t u = __float_as_uint(x);
  uint32_t s = (u >> 31) << 7;
  float ax = fabsf(x);
  if (ax < 0.015625f) {                 // subnormal target: m * 2^-9
    int m = (int)rintf(ax * 512.0f);    // RNE; 0..8
    return (m >= 8) ? (s | (1u << 3)) : (s | (uint32_t)m);
  }
  uint32_t v = u & 0x7FFFFFFFu;
  v += 0x7FFFFu + ((v >> 20) & 1u);     // RNE to 3 mantissa bits
  int e = (int)((v >> 23) & 255u) - 127;
  uint32_t m3 = (v >> 20) & 7u;
  return s | ((uint32_t)(e + 7) << 3) | m3;   // |x| <= ~2 -> no overflow
}
__device__ __forceinline__ float dec_e4m3(uint32_t b) {
  uint32_t s = b >> 7, e = (b >> 3) & 15u, m = b & 7u;
  float v = e ? __uint_as_float(((e + 120u) << 23) | (m << 20))
              : (float)m * 0.001953125f;      // m * 2^-9
  return s ? -v : v;
}

// ---------------------------------------------------------------------------
// K1: row L2-normalize (fp32), emit e4m3 copies scaled by SQK, diag =
// sum(dequant^2) (== the MFMA Gram diagonal).  Zeroes sums and d_out.
// ---------------------------------------------------------------------------
__global__ __launch_bounds__(256) void k_normalize(
    const float* __restrict__ u1, const float* __restrict__ u2,
    const float* __restrict__ i1, const float* __restrict__ i2,
    uint8_t* __restrict__ nb, float* __restrict__ diag,
    float* __restrict__ sums, float* __restrict__ out)
{
  int tid = threadIdx.x;
  int gid = blockIdx.x * 256 + tid;
  if (gid < 6 * NR) sums[gid] = 0.0f;
  if (gid == 0) out[0] = 0.0f;

  int w = tid >> 6, lane = tid & 63;
  int rowId = blockIdx.x * 4 + w;            // 0..32767
  int mi = rowId >> 13, r = rowId & (NR - 1);
  const float* src = (mi == 0) ? u1 : (mi == 1) ? u2 : (mi == 2) ? i1 : i2;
  const float2 v = *(const float2*)(src + (size_t)r * DD + lane * 2);
  float ss = v.x * v.x + v.y * v.y;
#pragma unroll
  for (int off = 32; off >= 1; off >>= 1) ss += __shfl_xor(ss, off, 64);
  float sc = SQK / fmaxf(sqrtf(ss), 1e-12f);
  uint32_t c0 = enc_e4m3(v.x * sc);
  uint32_t c1 = enc_e4m3(v.y * sc);
  uint8_t* dst = nb + (size_t)mi * NR * DD + (size_t)r * DD + lane * 2;
  *(uint16_t*)dst = (uint16_t)(c0 | (c1 << 8));
  float d0 = dec_e4m3(c0), d1 = dec_e4m3(c1);
  float dd = d0 * d0 + d1 * d1;
#pragma unroll
  for (int off = 32; off >= 1; off >>= 1) dd += __shfl_xor(dd, off, 64);
  if (lane == 0) diag[rowId] = dd;
}

// ---------------------------------------------------------------------------
// K2: Gram row-sums, MX-fp8 — r10 structure (768 blocks, 6 full Grams,
// triple-buffered 8KB tiles, counted vmcnt(2) + raw barrier per tile,
// launch_bounds(256,3)) + OUTPUT-SIDE software pipeline:
//   phase c issues its 4 MFMAs, then exps the PREVIOUS phase's accs
//   (pacc0..3, named regs) — no data dependency between bursts, so the
//   wave feeds matrix pipe and VALU/trans pipe concurrently instead of
//   stalling on MFMA results (r10: 164K cyc/SIMD ~= 3x serial per-wave
//   critical path; the MFMA->exp stall was on it).  Pipeline is carried
//   across tiles; pacc starts at -1e4 (exp2 -> exactly 0) and is drained
//   after the last tile.  LDS read offsets hoisted out of the tile loop.
// ---------------------------------------------------------------------------
__global__ __launch_bounds__(256, 3) void k_gram(
    const uint8_t* __restrict__ nb, float* __restrict__ sums)
{
  __shared__ alignas(16) uint8_t ldsB[3][64 * DD];   // 3 x 8 KB

  // bijective XCD-chunk swizzle: XCD k gets contiguous ids [k*96,(k+1)*96)
  int bid = (blockIdx.x & 7) * 96 + (blockIdx.x >> 3);
  int job = bid >> 7;          // 128 blocks per job
  int rem = bid & 127;
  int rb = rem >> 2;           // row-block 0..31 (256 rows each)
  int cs = rem & 3;            // col-chunk 0..3  (2048 cols each)
  const int ja[6] = {0, 0, 1, 2, 2, 3};
  const int jb[6] = {1, 0, 1, 3, 2, 3};
  const uint8_t* A = nb + (size_t)ja[job] * NR * DD;
  const uint8_t* B = nb + (size_t)jb[job] * NR * DD;
  float* out = sums + job * NR;

  int tid = threadIdx.x, w = tid >> 6, lane = tid & 63;
  int l15 = lane & 15, lg = lane >> 4;
  int rowBase = rb * 256 + w * 64;

  const char* Bb = (const char*)B;
  char* ldsbase = (char*)&ldsB[0][0];
  int jstart = cs * 2048;

  // hoisted swizzled LDS byte offsets (loop-invariant)
  int offL[4], offH[4];
#pragma unroll
  for (int c = 0; c < 4; ++c) {
    int r = c * 16 + l15;
    int base = r * 128 + lg * 32;
    int swz = (r & 7) << 4;
    offL[c] = base ^ swz;
    offH[c] = (base + 16) ^ swz;
  }

  // stage one 64-col tile (8KB): linear LDS dest, inverse-swizzled source
  // (rule #21).  2 x global_load_lds_dwordx4 per wave.
#define STAGE(dst, jt)                                                        \
  {                                                                           \
    const char* tbase = Bb + (size_t)(jstart + (jt) * 64) * 128;              \
    _Pragma("unroll")                                                         \
    for (int it = 0; it < 2; ++it) {                                          \
      int dbase = it * 4096 + w * 1024;                                       \
      int doff = dbase + lane * 16;                                           \
      int soff = doff ^ (((doff >> 7) & 7) << 4);                             \
      __builtin_amdgcn_global_load_lds(                                       \
          (const __attribute__((address_space(1))) void*)(tbase + soff),      \
          (__attribute__((address_space(3))) void*)((dst) + dbase),           \
          16, 0, 0);                                                          \
    }                                                                         \
  }

  // one c-phase: MFMAs for this phase, then exp/accumulate the previous
  // phase's accs (pacc0..3) — independent bursts, co-issueable.
#define COMPUTE(bufc)                                                         \
  {                                                                           \
    _Pragma("unroll")                                                         \
    for (int c = 0; c < 4; ++c) {                                             \
      int32x4 blo = *(const int32x4*)((bufc) + offL[c]);                      \
      int32x4 bhi = *(const int32x4*)((bufc) + offH[c]);                      \
      int32x8 b8 = __builtin_shufflevector(blo, bhi, 0, 1, 2, 3, 4, 5, 6, 7); \
      f32x4 z = {0.0f, 0.0f, 0.0f, 0.0f};                                     \
      f32x4 t0 = __builtin_amdgcn_mfma_scale_f32_16x16x128_f8f6f4(            \
          af[0], b8, z, 0, 0, 0, SCALE1, 0, SCALE1);                          \
      f32x4 t1 = __builtin_amdgcn_mfma_scale_f32_16x16x128_f8f6f4(            \
          af[1], b8, z, 0, 0, 0, SCALE1, 0, SCALE1);                          \
      f32x4 t2 = __builtin_amdgcn_mfma_scale_f32_16x16x128_f8f6f4(            \
          af[2], b8, z, 0, 0, 0, SCALE1, 0, SCALE1);                          \
      f32x4 t3 = __builtin_amdgcn_mfma_scale_f32_16x16x128_f8f6f4(            \
          af[3], b8, z, 0, 0, 0, SCALE1, 0, SCALE1);                          \
      _Pragma("unroll")                                                       \
      for (int j = 0; j < 4; ++j) {                                           \
        racc[0][j] += EXP2F(pacc0[j]);                                        \
        racc[1][j] += EXP2F(pacc1[j]);                                        \
        racc[2][j] += EXP2F(pacc2[j]);                                        \
        racc[3][j] += EXP2F(pacc3[j]);                                        \
      }                                                                       \
      pacc0 = t0; pacc1 = t1; pacc2 = t2; pacc3 = t3;                         \
    }                                                                         \
  }

  // prologue: stage tile 0; A-frag loads fly under it; one full drain.
  STAGE(ldsbase, 0);

  // A fragments: row rowBase+m*16+l15, k-bytes [lg*32, lg*32+32)
  int32x8 af[4];
#pragma unroll
  for (int m = 0; m < 4; ++m)
    af[m] = *(const int32x8*)(A + (size_t)(rowBase + m * 16 + l15) * DD + lg * 32);

  float racc[4][4];
#pragma unroll
  for (int m = 0; m < 4; ++m)
#pragma unroll
    for (int j = 0; j < 4; ++j) racc[m][j] = 0.0f;

  // output-pipeline state: exp2(-1e4) == 0.0f exactly -> first drain adds 0
  f32x4 pacc0 = {-1e4f, -1e4f, -1e4f, -1e4f};
  f32x4 pacc1 = pacc0, pacc2 = pacc0, pacc3 = pacc0;

  asm volatile("s_waitcnt vmcnt(0)" ::: "memory");
  __builtin_amdgcn_s_barrier();
  __builtin_amdgcn_sched_barrier(0);

  // main loop: counted-vmcnt pipeline, ONE raw barrier per tile
  int cur = 0;
  for (int jt = 0; jt < 31; ++jt) {
    int nxt = cur + 1; if (nxt == 3) nxt = 0;
    STAGE(ldsbase + nxt * 8192, jt + 1);   // 2 loads issued, stay in flight
    __builtin_amdgcn_sched_barrier(0);
    asm volatile("s_waitcnt vmcnt(2)" ::: "memory");  // stage(jt) retired
    __builtin_amdgcn_s_barrier();                     // ...in ALL waves
    __builtin_amdgcn_sched_barrier(0);
    COMPUTE(ldsbase + cur * 8192);
    cur = nxt;
  }
  // epilogue: tile 31 + pipeline drain
  __builtin_amdgcn_sched_barrier(0);
  asm volatile("s_waitcnt vmcnt(0)" ::: "memory");
  __builtin_amdgcn_s_barrier();
  __builtin_amdgcn_sched_barrier(0);
  COMPUTE(ldsbase + cur * 8192);
#pragma unroll
  for (int j = 0; j < 4; ++j) {
    racc[0][j] += EXP2F(pacc0[j]);
    racc[1][j] += EXP2F(pacc1[j]);
    racc[2][j] += EXP2F(pacc2[j]);
    racc[3][j] += EXP2F(pacc3[j]);
  }

  // row-sums: reduce over the 16 lanes (cols) in each lg group
#pragma unroll
  for (int off = 1; off < 16; off <<= 1)
#pragma unroll
    for (int m = 0; m < 4; ++m)
#pragma unroll
      for (int j = 0; j < 4; ++j)
        racc[m][j] += __shfl_xor(racc[m][j], off, 64);

  if (l15 == 0) {
#pragma unroll
    for (int m = 0; m < 4; ++m)
#pragma unroll
      for (int j = 0; j < 4; ++j)
        atomicAdd(&out[rowBase + m * 16 + lg * 4 + j], racc[m][j]);
  }
#undef STAGE
#undef COMPUTE
}

// ---------------------------------------------------------------------------
// K3: finalize.  4 rows per wave-iteration (16-lane groups, 8 B/lane loads);
// 4 shuffles per row-reduce instead of 6; log tail 4-way parallel.
// One atomic per block (256 total).
// ---------------------------------------------------------------------------
__global__ __launch_bounds__(256) void k_finalize(
    const uint8_t* __restrict__ nb, const float* __restrict__ diag,
    const float* __restrict__ sums, float* __restrict__ out)
{
  __shared__ float part[4];
  int tid = threadIdx.x, w = tid >> 6, lane = tid & 63;
  int l15 = lane & 15, g = lane >> 4;
  int waveId = blockIdx.x * 4 + w;        // 0..1023
  float local = 0.0f;

  for (int i = 0; i < 4; ++i) {
    int rowId = waveId * 16 + i * 4 + g;  // 0..16383
    int p = rowId >> 13, r = rowId & (NR - 1);
    const uint8_t* n1 = nb + (size_t)(2 * p) * NR * DD + (size_t)r * DD + l15 * 8;
    const uint8_t* n2 = n1 + (size_t)NR * DD;
    uint2 a = *(const uint2*)n1;          // 8 e4m3 values
    uint2 b = *(const uint2*)n2;
    float p0 = 0.0f;
#pragma unroll
    for (int k = 0; k < 4; ++k)
      p0 += EXP2F(dec_e4m3((a.x >> (8 * k)) & 0xFFu) *
                  dec_e4m3((b.x >> (8 * k)) & 0xFFu));
#pragma unroll
    for (int k = 0; k < 4; ++k)
      p0 += EXP2F(dec_e4m3((a.y >> (8 * k)) & 0xFFu) *
                  dec_e4m3((b.y >> (8 * k)) & 0xFFu));
    // reduce across the 16 lanes of this group
    p0 += __shfl_xor(p0, 1, 64);
    p0 += __shfl_xor(p0, 2, 64);
    p0 += __shfl_xor(p0, 4, 64);
    p0 += __shfl_xor(p0, 8, 64);

    if (l15 == 0) {
      const float* s12v = sums + (3 * p) * NR;
      const float* s11v = sums + (3 * p + 1) * NR;
      const float* s22v = sums + (3 * p + 2) * NR;
      float e1 = EXP2F(diag[(2 * p) * NR + r]);
      float e2 = EXP2F(diag[(2 * p + 1) * NR + r]);
      float s12 = s12v[r];
      float S1 = s12 + (s11v[r] - e1) + p0;
      float S2 = s12 + (s22v[r] - e2) + p0;
      local += logf(S1) + logf(S2) - 2.0f * logf(p0);
    }
  }
  // sum the four group-leaders (other lanes hold 0)
  local += __shfl_xor(local, 16, 64);
  local += __shfl_xor(local, 32, 64);
  if (lane == 0) part[w] = local;
  __syncthreads();
  if (tid == 0) {
    float t = part[0] + part[1] + part[2] + part[3];
    atomicAdd(out, 0.25f * t);
  }
}

// ---------------------------------------------------------------------------
extern "C" void kernel_launch(void* const* d_in, const int* in_sizes, int n_in,
                              void* d_out, int out_size, void* d_ws, size_t ws_size,
                              hipStream_t stream) {
  const float* u1 = (const float*)d_in[0];
  const float* u2 = (const float*)d_in[1];
  const float* i1 = (const float*)d_in[2];
  const float* i2 = (const float*)d_in[3];

  // ws layout: 4 e4m3 matrices (4 MB) | diag[4][NR] f32 | sums[6][NR] f32
  uint8_t* nb = (uint8_t*)d_ws;
  float* diag = (float*)((char*)d_ws + (size_t)4 * NR * DD);
  float* sums = diag + 4 * NR;
  float* out = (float*)d_out;

  k_normalize<<<NR * 4 / 4, 256, 0, stream>>>(u1, u2, i1, i2, nb, diag, sums, out);
  k_gram<<<768, 256, 0, stream>>>(nb, sums);
  k_finalize<<<256, 256, 0, stream>>>(nb, diag, sums, out);
}